// Round 7
// baseline (581.286 us; speedup 1.0000x reference)
//
#include <hip/hip_runtime.h>
#include <cstdint>
#include <cstddef>

typedef unsigned short u16;
typedef unsigned int u32;

typedef unsigned short u16x8 __attribute__((ext_vector_type(8)));
typedef __bf16 bf16x8 __attribute__((ext_vector_type(8)));
typedef float f32x4 __attribute__((ext_vector_type(4)));
typedef float f32x8 __attribute__((ext_vector_type(8)));

#define NB   128
#define NL   192
#define NTOK (NB * NL)   // 24576
#define DIM  512
#define HID  2048

static __device__ __forceinline__ float bf2f(u16 h) {
    union { u32 u; float f; } v; v.u = ((u32)h) << 16; return v.f;
}
static __device__ __forceinline__ u16 f2bf(float f) {
    union { float f; u32 u; } v; v.f = f;
    u32 u = v.u + 0x7FFF + ((v.u >> 16) & 1);  // RNE
    return (u16)(u >> 16);
}

// -------- weight transpose + cast: in f32 (K,N) -> out bf16 (N,K) --------
__global__ void transpose_f2b(const float* __restrict__ in, u16* __restrict__ out,
                              int K, int N) {
    __shared__ float tile[32][33];
    int tx = threadIdx.x & 31, ty = threadIdx.x >> 5;  // 32 x 8
    int n0 = blockIdx.x * 32, k0 = blockIdx.y * 32;
#pragma unroll
    for (int i = 0; i < 4; i++)
        tile[ty + i * 8][tx] = in[(size_t)(k0 + ty + i * 8) * N + n0 + tx];
    __syncthreads();
#pragma unroll
    for (int i = 0; i < 4; i++)
        out[(size_t)(n0 + ty + i * 8) * K + k0 + tx] = f2bf(tile[tx][ty + i * 8]);
}

// -------- embedding: emb[t=l*B+b][d] = sum of 5 f32 tables; f32 + bf16 out ----
static __device__ __forceinline__ void add8f(float* acc, const float* p) {
    f32x8 v = *(const f32x8*)p;
#pragma unroll
    for (int i = 0; i < 8; i++) acc[i] += v[i];
}

__global__ void embed_kernel(const int* __restrict__ element, const int* __restrict__ aroma,
                             const int* __restrict__ charge, const int* __restrict__ segment,
                             const float* __restrict__ pe, const float* __restrict__ E_elem,
                             const float* __restrict__ E_charge, const float* __restrict__ E_aroma,
                             const float* __restrict__ E_seg,
                             float* __restrict__ emb32, u16* __restrict__ emb16) {
    int t = blockIdx.x * 4 + (threadIdx.x >> 6);  // one wave per token
    int lane = threadIdx.x & 63;
    int l = t >> 7, b = t & 127;                  // t = l*128 + b
    int d = lane * 8;
    int idx = b * NL + l;
    int e = element[idx];
    int a = aroma[idx];
    int c = charge[idx] + 6;
    int s = segment[idx];
    float acc[8] = {0, 0, 0, 0, 0, 0, 0, 0};
    add8f(acc, E_elem  + (size_t)e * DIM + d);
    add8f(acc, pe      + (size_t)l * DIM + d);
    add8f(acc, E_aroma + (size_t)a * DIM + d);
    add8f(acc, E_charge+ (size_t)c * DIM + d);
    add8f(acc, E_seg   + (size_t)s * DIM + d);
    f32x8 o32; u16x8 o16;
#pragma unroll
    for (int i = 0; i < 8; i++) { o32[i] = acc[i]; o16[i] = f2bf(acc[i]); }
    *(f32x8*)(emb32 + (size_t)t * DIM + d) = o32;
    *(u16x8*)(emb16 + (size_t)t * DIM + d) = o16;
}

// -------- GEMM: C[M,N] = A[M,K] @ BT[N,K]^T (+f32 bias, relu, bf16/f32 resid) --
// Round-7: 8-phase template with CORRECTED stage ledger (round-6 raced:
// p1/p2 staged A[2t+3] into Ao while p5-p8 of the SAME iter still read
// A[2t+1] from Ao -> absmax 5.7).
//   256x256 tile, 8 waves (2M x 4N), per-wave 128x64 = acc[8][4].
//   LDS 128 KB: Ae/Ao/Be/Bo 32 KB bufs (K-tile kt -> buf kt&1).
//   Iter t computes kt {2t, 2t+1}; reads: Be+Ae q0 @p1, Ae q1-3 @p2-4,
//   Bo+Ao q0 @p5, Ao q1-3 @p6-8.  Buffer freedom: Be after p1, Ae after p4,
//   Bo after p5, Ao after p8 (prev iter).
// Stage ledger (iter t):
//   p1 A[2t+1]h0->Ao   p2 A[2t+1]h1->Ao   (Ao freed at prev-iter p8 OK)
//   p3 B[2t+2]h0->Be   p4 B[2t+2]h1->Be   (Be freed at p1 OK)
//   p5 A[2t+2]h0->Ae   p6 A[2t+2]h1->Ae   (Ae freed at p4 OK)
//   p7 B[2t+3]h0->Bo   p8 B[2t+3]h1->Bo   (Bo freed at p5 OK)
// Counted waits (age accounting; never 0 in-loop):
//   p4 vmcnt(4): needs {B[2t+1] (prev p7/p8), A[2t+1] (p1/p2)} landed before
//     p5 reads; younger outstanding = p3/p4's 4 loads -> N=4.
//   p8 vmcnt(4): needs {B[2t+2] (p3/p4), A[2t+2] (p5/p6)} landed before next
//     iter p1 reads; younger = p7/p8's 4 loads -> N=4.
//   Prologue: stage A[0],B[0],B[1] (12 loads); vmcnt(4) -> A[0],B[0] landed,
//     B[1] stays in flight.  Last iter: only p1/p2 stage (A-odd still needed);
//     p4 -> vmcnt(0); p8 -> no wait (epilogue __syncthreads drains).
// Landing-vs-read hazards: every overwritten buffer's final ds_reads are
//   register-landed at an lgkmcnt(0) before the barrier that precedes the
//   overwriting stage's issue (checked per-buffer above).
// Swizzle: LDS[row][c] holds global chunk c^(row&7) via pre-swizzled source,
//   linear GLL dest (m104); reads chunk (ks*4+fq)^(fr&7). 0-conflict (meas.).
// Requires M%256==0, N%256==0, K%128==0, K/128>=2 (all our shapes).
__global__ __launch_bounds__(512, 2) void gemm_bt(
    const u16* __restrict__ A, const u16* __restrict__ BT,
    const float* __restrict__ bias, const u16* __restrict__ resid16,
    const float* __restrict__ resid32,
    u16* __restrict__ C, int M, int N, int K, int do_relu) {
    // staging: Ae @0, Ao @16384, Be @32768, Bo @49152 (u16 units; 32 KB each).
    // epilogue reuses smem as [128][264] u16 (67.5 KB), two passes.
    __shared__ __align__(16) u16 smem[65536];

    const int tid  = threadIdx.x;
    const int wave = tid >> 6;
    const int lane = tid & 63;

    // XCD-aware swizzle (bijective when nwg%8==0 -- all our grids), N-fastest.
    const int nwg = gridDim.x;
    const int bid = blockIdx.x;
    const int wg  = ((nwg & 7) == 0) ? ((bid & 7) * (nwg >> 3) + (bid >> 3)) : bid;
    const int nt  = N >> 8;                 // N-tiles of 256
    const int m0  = (wg / nt) * 256;
    const int n0  = (wg % nt) * 256;

    const int wmh = wave >> 2;          // 0..1 : wave's A row-half (128 rows)
    const int wnq = wave & 3;           // 0..3 : wave's B row-quarter (64 rows)
    const int fr  = lane & 15;          // fragment row/col
    const int fq  = lane >> 4;          // fragment k-quad
    const int ck0 = ((fq ^ (fr & 7)) * 8);         // swizzled read chunk, ks=0
    const int ck1 = (((4 | fq) ^ (fr & 7)) * 8);   // ks=1

    // staging: 8 chunks of 16B per row, 64 rows per GLL (8 KB / 512 threads).
    const int sRow = tid >> 3;                       // 0..63
    const int sChk = ((tid & 7) ^ (sRow & 7)) * 8;   // pre-swizzled SOURCE chunk
    const int lin  = sRow * 64 + (tid & 7) * 8;      // LINEAR lds dest (u16)

    const u16* Asrc = A  + (size_t)(m0 + sRow) * K + sChk;
    const u16* Bsrc = BT + (size_t)(n0 + sRow) * K + sChk;

    f32x4 acc[8][4] = {};

#define GLL(gp, lp) __builtin_amdgcn_global_load_lds(                            \
        (const __attribute__((address_space(1))) void*)(gp),                     \
        (__attribute__((address_space(3))) void*)(lp), 16, 0, 0)
// stage half h (0/1) of k-tile kt: 2 GLL (rows h*128+{0,64}+sRow)
#define STG_A(kt, h) do {                                                        \
    GLL(Asrc + (size_t)(kt)*64 + (size_t)((h)*128     )*K,                       \
        &smem[((kt)&1)*16384 + ((h)*128     )*64 + lin]);                        \
    GLL(Asrc + (size_t)(kt)*64 + (size_t)((h)*128 + 64)*K,                       \
        &smem[((kt)&1)*16384 + ((h)*128 + 64)*64 + lin]);                        \
} while (0)
#define STG_B(kt, h) do {                                                        \
    GLL(Bsrc + (size_t)(kt)*64 + (size_t)((h)*128     )*K,                       \
        &smem[32768 + ((kt)&1)*16384 + ((h)*128     )*64 + lin]);                \
    GLL(Bsrc + (size_t)(kt)*64 + (size_t)((h)*128 + 64)*K,                       \
        &smem[32768 + ((kt)&1)*16384 + ((h)*128 + 64)*64 + lin]);                \
} while (0)

#define BARRIER() asm volatile("s_barrier" ::: "memory")
#define LGKM0() do { asm volatile("s_waitcnt lgkmcnt(0)" ::: "memory");          \
                     __builtin_amdgcn_sched_barrier(0); } while (0)

#define LOAD_BG(Bb) do {                                                         \
    _Pragma("unroll") for (int j = 0; j < 4; ++j) {                              \
        bg[j][0] = *(const bf16x8*)&(Bb)[(wnq*64 + j*16 + fr)*64 + ck0];         \
        bg[j][1] = *(const bf16x8*)&(Bb)[(wnq*64 + j*16 + fr)*64 + ck1];         \
    } } while (0)
#define LOAD_AF(Ab, q) do {                                                      \
    _Pragma("unroll") for (int ii = 0; ii < 2; ++ii) {                           \
        af[ii][0] = *(const bf16x8*)&(Ab)[(wmh*128 + ((q)*2+ii)*16 + fr)*64 + ck0]; \
        af[ii][1] = *(const bf16x8*)&(Ab)[(wmh*128 + ((q)*2+ii)*16 + fr)*64 + ck1]; \
    } } while (0)
#define MFMA_Q(q) do {                                                           \
    __builtin_amdgcn_s_setprio(1);                                               \
    _Pragma("unroll") for (int ii = 0; ii < 2; ++ii)                             \
    _Pragma("unroll") for (int j = 0; j < 4; ++j) {                              \
        acc[(q)*2+ii][j] = __builtin_amdgcn_mfma_f32_16x16x32_bf16(              \
            af[ii][0], bg[j][0], acc[(q)*2+ii][j], 0, 0, 0);                     \
        acc[(q)*2+ii][j] = __builtin_amdgcn_mfma_f32_16x16x32_bf16(              \
            af[ii][1], bg[j][1], acc[(q)*2+ii][j], 0, 0, 0);                     \
    }                                                                            \
    __builtin_amdgcn_s_setprio(0); } while (0)

    const u16* Ae = &smem[0];
    const u16* Ao = &smem[16384];
    const u16* Be = &smem[32768];
    const u16* Bo = &smem[49152];

    const int nI = K >> 7;   // iterations of 2 K-tiles; >= 2 required
    // prologue: 12 loads {A[0](4), B[0](4), B[1](4)}; vmcnt(4) -> A[0],B[0]
    // landed, B[1] (4 youngest) stays in flight.
    STG_A(0, 0); STG_A(0, 1); STG_B(0, 0); STG_B(0, 1);
    STG_B(1, 0); STG_B(1, 1);
    asm volatile("s_waitcnt vmcnt(4)\n\ts_barrier" ::: "memory");

    for (int t = 0; t < nI; ++t) {
        const int k0t = 2 * t;
        const bool st = (t + 1 < nI);
        bf16x8 bg[4][2], af[2][2];
        // ---- P1: B(even)+A(even,q0) reads; stage A[2t+1] h0 -> Ao ----
        LOAD_BG(Be); LOAD_AF(Ae, 0);
        STG_A(k0t + 1, 0);
        asm volatile("s_waitcnt lgkmcnt(8)" ::: "memory");
        BARRIER(); LGKM0(); MFMA_Q(0); BARRIER();
        // ---- P2: stage A[2t+1] h1 -> Ao ----
        LOAD_AF(Ae, 1);
        STG_A(k0t + 1, 1);
        BARRIER(); LGKM0(); MFMA_Q(1); BARRIER();
        // ---- P3: stage B[2t+2] h0 -> Be (freed at p1) ----
        LOAD_AF(Ae, 2);
        if (st) STG_B(k0t + 2, 0);
        BARRIER(); LGKM0(); MFMA_Q(2); BARRIER();
        // ---- P4: stage B[2t+2] h1; vmcnt(4): {B[2t+1],A[2t+1]} landed,
        //          p3/p4's B[2t+2] (4 loads) stay in flight ----
        LOAD_AF(Ae, 3);
        if (st) {
            STG_B(k0t + 2, 1);
            asm volatile("s_waitcnt vmcnt(4)" ::: "memory");
        } else {
            asm volatile("s_waitcnt vmcnt(0)" ::: "memory");
        }
        BARRIER(); LGKM0(); MFMA_Q(3); BARRIER();
        // ---- P5: B(odd)+A(odd,q0) reads; stage A[2t+2] h0 -> Ae (freed p4) --
        LOAD_BG(Bo); LOAD_AF(Ao, 0);
        if (st) STG_A(k0t + 2, 0);
        asm volatile("s_waitcnt lgkmcnt(8)" ::: "memory");
        BARRIER(); LGKM0(); MFMA_Q(0); BARRIER();
        // ---- P6: stage A[2t+2] h1 -> Ae ----
        LOAD_AF(Ao, 1);
        if (st) STG_A(k0t + 2, 1);
        BARRIER(); LGKM0(); MFMA_Q(1); BARRIER();
        // ---- P7: stage B[2t+3] h0 -> Bo (freed at p5) ----
        LOAD_AF(Ao, 2);
        if (st) STG_B(k0t + 3, 0);
        BARRIER(); LGKM0(); MFMA_Q(2); BARRIER();
        // ---- P8: stage B[2t+3] h1; vmcnt(4): {B[2t+2],A[2t+2]} landed for
        //          next iter p1; p7/p8's B[2t+3] (4 loads) stay in flight ----
        LOAD_AF(Ao, 3);
        if (st) {
            STG_B(k0t + 3, 1);
            asm volatile("s_waitcnt vmcnt(4)" ::: "memory");
        }
        BARRIER(); LGKM0(); MFMA_Q(3); BARRIER();
    }
#undef STG_A
#undef STG_B
#undef GLL
#undef LOAD_BG
#undef LOAD_AF
#undef MFMA_Q

    // ---- epilogue: bias/relu/resid in-register, two-pass LDS staging ----
    // ([128][264] u16 = 67.5 KB; staging buffers are dead).  C/D layout:
    // col = lane&15, row = fq*4 + reg.
#define CSTR 264
#pragma unroll
    for (int h = 0; h < 2; ++h) {
        __syncthreads();   // pass 0: also drains K-loop; pass 1: store done
        if (wmh == h) {
#pragma unroll
            for (int j = 0; j < 4; j++) {
                int n = n0 + wnq * 64 + j * 16 + fr;
                float bv = bias[n];
#pragma unroll
                for (int i = 0; i < 8; i++) {
#pragma unroll
                    for (int r = 0; r < 4; r++) {
                        int m = m0 + h * 128 + i * 16 + fq * 4 + r;
                        float v = acc[i][j][r] + bv;
                        if (do_relu) v = fmaxf(v, 0.0f);
                        if (resid16) v += bf2f(resid16[(size_t)m * N + n]);
                        if (resid32) v += resid32[(size_t)m * N + n];
                        smem[(i * 16 + fq * 4 + r) * CSTR + wnq * 64 + j * 16 + fr] = f2bf(v);
                    }
                }
            }
        }
        __syncthreads();
        const int erow = tid >> 5;         // 0..15
        const int ecol = (tid & 31) * 8;   // 32 lanes x 8 u16 = 256 cols
#pragma unroll
        for (int rr = 0; rr < 8; ++rr) {
            int row = rr * 16 + erow;
            *(u16x8*)(C + (size_t)(m0 + h * 128 + row) * N + n0 + ecol) =
                *(const u16x8*)(&smem[row * CSTR + ecol]);
        }
    }
#undef CSTR
#undef BARRIER
#undef LGKM0
}

// -------- aggregation + final residual (in-place on d_out, f32) --------
// out[t=l*B+b][d] = emb32[t][d] + sum_m (bond[b,l,m]!=l) * msg[bond*B+b][d]
__global__ void agg_kernel(const float* __restrict__ emb32, const u16* __restrict__ msg,
                           const int* __restrict__ bond, float* __restrict__ out) {
    int t = blockIdx.x * 4 + (threadIdx.x >> 6);  // one wave per token
    int lane = threadIdx.x & 63;
    int l = t >> 7, b = t & 127;
    int d = lane * 8;
    float acc[8];
    {
        f32x8 v = *(const f32x8*)(emb32 + (size_t)t * DIM + d);
#pragma unroll
        for (int i = 0; i < 8; i++) acc[i] = v[i];
    }
    const int* bp = bond + ((size_t)b * NL + l) * 6;
#pragma unroll
    for (int m = 0; m < 6; m++) {
        int j = bp[m];
        if (j != l) {  // wave-uniform branch
            u16x8 g = *(const u16x8*)(msg + ((size_t)j * NB + b) * DIM + d);
#pragma unroll
            for (int i = 0; i < 8; i++) acc[i] += bf2f(g[i]);
        }
    }
    f32x8 o;
#pragma unroll
    for (int i = 0; i < 8; i++) o[i] = acc[i];
    *(f32x8*)(out + (size_t)t * DIM + d) = o;
}

extern "C" void kernel_launch(void* const* d_in, const int* in_sizes, int n_in,
                              void* d_out, int out_size, void* d_ws, size_t ws_size,
                              hipStream_t stream) {
    const int* element = (const int*)d_in[0];
    const int* bond    = (const int*)d_in[1];
    const int* aroma   = (const int*)d_in[2];
    const int* charge  = (const int*)d_in[3];
    const int* segment = (const int*)d_in[4];
    const float* pe      = (const float*)d_in[5];
    const float* E_elem  = (const float*)d_in[6];
    const float* E_charge= (const float*)d_in[7];
    const float* E_aroma = (const float*)d_in[8];
    const float* E_seg   = (const float*)d_in[9];
    const float* W1 = (const float*)d_in[10];
    const float* b1 = (const float*)d_in[11];
    const float* W2 = (const float*)d_in[12];
    const float* b2 = (const float*)d_in[13];
    const float* W3 = (const float*)d_in[14];
    const float* b3 = (const float*)d_in[15];
    const float* W4 = (const float*)d_in[16];
    const float* b4 = (const float*)d_in[17];
    const float* W5 = (const float*)d_in[18];
    const float* b5 = (const float*)d_in[19];

    // f32 emb lives in d_out (50 MiB); agg rewrites d_out in place at the end.
    float* emb32 = (float*)d_out;

    // dynamic ws layout — never exceed ws_size
    char* ws = (char*)d_ws;
    size_t woff = 0;
    auto take = [&](size_t bytes) -> u16* {
        u16* p = (u16*)(ws + woff);
        woff += (bytes + 255) & ~(size_t)255;
        return p;
    };
    u16* W1T = take((size_t)HID * DIM * 2);   // 2048x512 bf16
    u16* W2T = take((size_t)DIM * HID * 2);   // 512x2048
    u16* W3T = take((size_t)HID * DIM * 2);
    u16* W4T = take((size_t)DIM * HID * 2);
    u16* W5T = take((size_t)DIM * DIM * 2);
    u16* emb16 = take((size_t)NTOK * DIM * 2);  // 24 MiB
    u16* msg   = take((size_t)NTOK * DIM * 2);  // 24 MiB

    // pick largest M-chunk that fits: h(CM x HID) + xa,xb(CM x DIM), bf16.
    // CM must be a multiple of 256 (gemm tile height).
    static const int ncs[] = {1, 2, 3, 4, 6, 8, 12, 16, 24, 32, 48, 96};
    int CM = 256;
    for (int nc : ncs) {
        int cm = NTOK / nc;
        if (cm % 256 != 0) continue;
        size_t need = woff + ((size_t)cm * HID * 2 + 256)
                           + ((size_t)cm * DIM * 2 + 256) * 2;
        if (need <= ws_size) { CM = cm; break; }
    }
    u16* hC  = take((size_t)CM * HID * 2);
    u16* xaC = take((size_t)CM * DIM * 2);
    u16* xbC = take((size_t)CM * DIM * 2);

    // weight transposes + cast: f32 (K,N) -> bf16 (N,K)
    transpose_f2b<<<dim3(HID / 32, DIM / 32), 256, 0, stream>>>(W1, W1T, DIM, HID);
    transpose_f2b<<<dim3(DIM / 32, HID / 32), 256, 0, stream>>>(W2, W2T, HID, DIM);
    transpose_f2b<<<dim3(HID / 32, DIM / 32), 256, 0, stream>>>(W3, W3T, DIM, HID);
    transpose_f2b<<<dim3(DIM / 32, HID / 32), 256, 0, stream>>>(W4, W4T, HID, DIM);
    transpose_f2b<<<dim3(DIM / 32, DIM / 32), 256, 0, stream>>>(W5, W5T, DIM, DIM);

    embed_kernel<<<NTOK / 4, 256, 0, stream>>>(element, aroma, charge, segment, pe,
                                               E_elem, E_charge, E_aroma, E_seg,
                                               emb32, emb16);

    // MLP per M-chunk: x += relu(x@W1+b1)@W2+b2 ; x += relu(x@W3+b3)@W4+b4 ; msg = x@W5+b5
    // All GEMMs: 256x256 tiles (grids: W1/W3 768 blocks, W2/W4/W5 192; %8==0).
    for (int c0 = 0; c0 < NTOK; c0 += CM) {
        const u16* x16 = emb16 + (size_t)c0 * DIM;
        const float* x32 = emb32 + (size_t)c0 * DIM;
        u16* msgC = msg + (size_t)c0 * DIM;
        int mt = CM / 256;
        gemm_bt<<<dim3(mt * (HID / 256)), 512, 0, stream>>>(x16, W1T, b1, nullptr, nullptr, hC,  CM, HID, DIM, 1);
        gemm_bt<<<dim3(mt * (DIM / 256)), 512, 0, stream>>>(hC,  W2T, b2, nullptr, x32,     xaC, CM, DIM, HID, 0);
        gemm_bt<<<dim3(mt * (HID / 256)), 512, 0, stream>>>(xaC, W3T, b3, nullptr, nullptr, hC,  CM, HID, DIM, 1);
        gemm_bt<<<dim3(mt * (DIM / 256)), 512, 0, stream>>>(hC,  W4T, b4, xaC,    nullptr,  xbC, CM, DIM, HID, 0);
        gemm_bt<<<dim3(mt * (DIM / 256)), 512, 0, stream>>>(xbC, W5T, b5, nullptr, nullptr, msgC, CM, DIM, DIM, 0);
    }

    agg_kernel<<<NTOK / 4, 256, 0, stream>>>(emb32, msg, bond, (float*)d_out);
}

// Round 8
// 488.207 us; speedup vs baseline: 1.1907x; 1.1907x over previous
//
#include <hip/hip_runtime.h>
#include <cstdint>
#include <cstddef>

typedef unsigned short u16;
typedef unsigned int u32;

typedef unsigned short u16x8 __attribute__((ext_vector_type(8)));
typedef __bf16 bf16x8 __attribute__((ext_vector_type(8)));
typedef float f32x4 __attribute__((ext_vector_type(4)));
typedef float f32x8 __attribute__((ext_vector_type(8)));

#define NB   128
#define NL   192
#define NTOK (NB * NL)   // 24576
#define DIM  512
#define HID  2048

// Activation tiling: bf16 buffers consumed as GEMM A-operands are stored as
// [M/256][K/64][256][64] (32 KB tiles). Offset of element (m,k) in a buffer
// with row-length K: ((m>>8)*(K>>6) + (k>>6))*16384 + (m&255)*64 + (k&63).
// Rationale: per K-tile a GEMM block then stages ONE contiguous 32 KB block
// (4 sequential 8-KB GLL spans) instead of 256 scattered 128-B reads at 4 KB
// stride -- the DRAM-efficiency killer that pinned W2-class at ~90 us across
// 7 schedule variants (FETCH 82 MB at only ~1.2 TB/s effective).

static __device__ __forceinline__ float bf2f(u16 h) {
    union { u32 u; float f; } v; v.u = ((u32)h) << 16; return v.f;
}
static __device__ __forceinline__ u16 f2bf(float f) {
    union { float f; u32 u; } v; v.f = f;
    u32 u = v.u + 0x7FFF + ((v.u >> 16) & 1);  // RNE
    return (u16)(u >> 16);
}

// -------- weight transpose + cast: in f32 (K,N) -> out bf16 (N,K) --------
__global__ void transpose_f2b(const float* __restrict__ in, u16* __restrict__ out,
                              int K, int N) {
    __shared__ float tile[32][33];
    int tx = threadIdx.x & 31, ty = threadIdx.x >> 5;  // 32 x 8
    int n0 = blockIdx.x * 32, k0 = blockIdx.y * 32;
#pragma unroll
    for (int i = 0; i < 4; i++)
        tile[ty + i * 8][tx] = in[(size_t)(k0 + ty + i * 8) * N + n0 + tx];
    __syncthreads();
#pragma unroll
    for (int i = 0; i < 4; i++)
        out[(size_t)(n0 + ty + i * 8) * K + k0 + tx] = f2bf(tile[tx][ty + i * 8]);
}

// -------- embedding: emb[t=l*B+b][d] = sum of 5 f32 tables ----
// emb32 row-major f32 (agg/resid32 consumer); emb16 TILED bf16 (W1's A).
static __device__ __forceinline__ void add8f(float* acc, const float* p) {
    f32x8 v = *(const f32x8*)p;
#pragma unroll
    for (int i = 0; i < 8; i++) acc[i] += v[i];
}

__global__ void embed_kernel(const int* __restrict__ element, const int* __restrict__ aroma,
                             const int* __restrict__ charge, const int* __restrict__ segment,
                             const float* __restrict__ pe, const float* __restrict__ E_elem,
                             const float* __restrict__ E_charge, const float* __restrict__ E_aroma,
                             const float* __restrict__ E_seg,
                             float* __restrict__ emb32, u16* __restrict__ emb16) {
    int t = blockIdx.x * 4 + (threadIdx.x >> 6);  // one wave per token
    int lane = threadIdx.x & 63;
    int l = t >> 7, b = t & 127;                  // t = l*128 + b
    int d = lane * 8;
    int idx = b * NL + l;
    int e = element[idx];
    int a = aroma[idx];
    int c = charge[idx] + 6;
    int s = segment[idx];
    float acc[8] = {0, 0, 0, 0, 0, 0, 0, 0};
    add8f(acc, E_elem  + (size_t)e * DIM + d);
    add8f(acc, pe      + (size_t)l * DIM + d);
    add8f(acc, E_aroma + (size_t)a * DIM + d);
    add8f(acc, E_charge+ (size_t)c * DIM + d);
    add8f(acc, E_seg   + (size_t)s * DIM + d);
    f32x8 o32; u16x8 o16;
#pragma unroll
    for (int i = 0; i < 8; i++) { o32[i] = acc[i]; o16[i] = f2bf(acc[i]); }
    *(f32x8*)(emb32 + (size_t)t * DIM + d) = o32;
    // tiled: DIM=512 -> 8 k-tiles per 256-row m-tile
    size_t ti = ((size_t)(t >> 8) * 8 + (d >> 6)) * 16384 + (size_t)(t & 255) * 64 + (d & 63);
    *(u16x8*)(emb16 + ti) = o16;
}

// -------- GEMM: C[M,N] = A_tiled[M,K] @ BT[N,K]^T (+bias, relu, resid) --------
// Round-8 = round-3 loop (best verified: 1 barrier/K-tile, BK=64, dbuf,
// 256x256 tile, 8 waves 2Mx4N acc[8][4]) + TILED A-operand + tiled C mode.
//   A is [M/256][K/64][256][64]: per K-tile the 4 A-GLLs read one contiguous
//   32 KB block (8 KB sequential spans) -> DRAM-friendly streaming.
//   B stays row-major [N][K] (2 MB, L2-hot after first touch).
// Schedule (verified round 3): one vmcnt(0)+s_barrier per 64-K tile; all 8
//   GLLs for t+1 issued right after (full-tile issue->wait distance); interior
//   24 ds_read_b128 + 64 MFMA compiler-scheduled; setprio around MFMA.
// Swizzle: LDS[row][c] holds global chunk c^(row&7) via pre-swizzled source,
//   linear GLL dest (m104); reads chunk (ks*4+fq)^(fr&7). 0-conflict (meas.).
// out_tiled: C written as [M/256][N/64][256][64] (when feeding the next GEMM);
//   else row-major (msg, consumed by agg). resid16 is tiled (xaC); resid32
//   row-major f32 (emb32).
// Requires M%256==0, N%256==0, K%64==0 (all our shapes).
__global__ __launch_bounds__(512, 2) void gemm_bt(
    const u16* __restrict__ A, const u16* __restrict__ BT,
    const float* __restrict__ bias, const u16* __restrict__ resid16,
    const float* __restrict__ resid32,
    u16* __restrict__ C, int M, int N, int K, int do_relu, int out_tiled) {
    // staging: A[2][256*64] @ 0 (64 KB), B[2][256*64] @ 32768 u16 (64 KB).
    // epilogue reuses smem as [256][264] u16 = 132 KB.
    __shared__ __align__(16) u16 smem[256 * 264];

    const int tid  = threadIdx.x;
    const int wave = tid >> 6;
    const int lane = tid & 63;

    // XCD-aware swizzle (bijective when nwg%8==0 -- all our grids), N-fastest.
    const int nwg = gridDim.x;
    const int bid = blockIdx.x;
    const int wg  = ((nwg & 7) == 0) ? ((bid & 7) * (nwg >> 3) + (bid >> 3)) : bid;
    const int nt  = N >> 8;                 // N-tiles of 256
    const int m0  = (wg / nt) * 256;
    const int n0  = (wg % nt) * 256;

    const int wmh = wave >> 2;          // 0..1 : wave's A row-half (128 rows)
    const int wnq = wave & 3;           // 0..3 : wave's B row-quarter (64 rows)
    const int fr  = lane & 15;          // fragment row/col
    const int fq  = lane >> 4;          // fragment k-quad
    const int ck0 = ((fq ^ (fr & 7)) * 8);         // swizzled read chunk, ks=0
    const int ck1 = (((4 | fq) ^ (fr & 7)) * 8);   // ks=1

    // staging: 8 chunks of 16B per row, 64 rows per GLL round.
    const int sRow = tid >> 3;                       // 0..63
    const int sChk = ((tid & 7) ^ (sRow & 7)) * 8;   // pre-swizzled SOURCE chunk
    const int ldst = sRow * 64 + (tid & 7) * 8;      // LINEAR lds dest (u16)

    // A: tiled base for this block's 256-row panel; per K-tile kt the slice is
    // Atile + kt*16384 (contiguous 32 KB), row-group g at +g*4096.
    const u16* Atile = A + ((size_t)(m0 >> 8) * (K >> 6)) * 16384 + sRow * 64 + sChk;
    const u16* Bsrc  = BT + (size_t)(n0 + sRow) * K + sChk;

    f32x4 acc[8][4] = {};

#define GLL(gp, lp) __builtin_amdgcn_global_load_lds(                            \
        (const __attribute__((address_space(1))) void*)(gp),                     \
        (__attribute__((address_space(3))) void*)(lp), 16, 0, 0)
#define STAGE(buf, kt) do {                                                      \
    GLL(Atile + (size_t)(kt) * 16384,         &smem[(buf)*16384 +         ldst]); \
    GLL(Atile + (size_t)(kt) * 16384 +  4096, &smem[(buf)*16384 +  4096 + ldst]); \
    GLL(Atile + (size_t)(kt) * 16384 +  8192, &smem[(buf)*16384 +  8192 + ldst]); \
    GLL(Atile + (size_t)(kt) * 16384 + 12288, &smem[(buf)*16384 + 12288 + ldst]); \
    GLL(Bsrc + (size_t)(kt) * 64,                 &smem[32768 + (buf)*16384 +         ldst]); \
    GLL(Bsrc + (size_t)(kt) * 64 + (size_t) 64*K, &smem[32768 + (buf)*16384 +  4096 + ldst]); \
    GLL(Bsrc + (size_t)(kt) * 64 + (size_t)128*K, &smem[32768 + (buf)*16384 +  8192 + ldst]); \
    GLL(Bsrc + (size_t)(kt) * 64 + (size_t)192*K, &smem[32768 + (buf)*16384 + 12288 + ldst]); \
} while (0)

    const int nk = K >> 6;   // 8 or 32 here
    STAGE(0, 0);             // tile 0 in flight (8 GLL)

    for (int t = 0; t < nk; ++t) {
        // boundary: tile t's 8 loads are the only outstanding vmem; issued a
        // full tile before this wait.
        asm volatile("s_waitcnt vmcnt(0)\n\ts_barrier" ::: "memory");
        if (t + 1 < nk) STAGE((t + 1) & 1, t + 1);   // in flight across tile t

        const u16* Ab = &smem[(t & 1) * 16384];
        const u16* Bb = &smem[32768 + (t & 1) * 16384];
#pragma unroll
        for (int s = 0; s < 2; ++s) {
            const int ck = s ? ck1 : ck0;
            bf16x8 af[8], bg[4];
#pragma unroll
            for (int i = 0; i < 8; ++i)
                af[i] = *(const bf16x8*)(&Ab[(wmh * 128 + i * 16 + fr) * 64 + ck]);
#pragma unroll
            for (int j = 0; j < 4; ++j)
                bg[j] = *(const bf16x8*)(&Bb[(wnq * 64 + j * 16 + fr) * 64 + ck]);

            __builtin_amdgcn_s_setprio(1);
#pragma unroll
            for (int i = 0; i < 8; ++i)
#pragma unroll
                for (int j = 0; j < 4; ++j)
                    acc[i][j] = __builtin_amdgcn_mfma_f32_16x16x32_bf16(
                        af[i], bg[j], acc[i][j], 0, 0, 0);
            __builtin_amdgcn_s_setprio(0);
        }
    }
#undef STAGE
#undef GLL

    // ---- epilogue: bias/relu/resid in-register, stage bf16 tile to LDS, ----
    // ---- then coalesced stores (tiled or row-major). -----------------------
    // C/D layout: col = lane&15 (n), row = (lane>>4)*4 + reg (m)
    __syncthreads();   // all waves past final LDS reads; all vmem drained
#define CSTR 264
#pragma unroll
    for (int j = 0; j < 4; j++) {
        int n = n0 + wnq * 64 + j * 16 + fr;
        float bv = bias[n];
#pragma unroll
        for (int i = 0; i < 8; i++) {
#pragma unroll
            for (int r = 0; r < 4; r++) {
                int m = m0 + wmh * 128 + i * 16 + fq * 4 + r;
                float v = acc[i][j][r] + bv;
                if (do_relu) v = fmaxf(v, 0.0f);
                if (resid16) {   // resid16 buffers are TILED (xaC)
                    size_t ri = ((size_t)(m >> 8) * (N >> 6) + (n >> 6)) * 16384
                              + (size_t)(m & 255) * 64 + (n & 63);
                    v += bf2f(resid16[ri]);
                }
                if (resid32) v += resid32[(size_t)m * N + n];   // row-major f32
                smem[(wmh * 128 + i * 16 + fq * 4 + r) * CSTR + wnq * 64 + j * 16 + fr] = f2bf(v);
            }
        }
    }
    __syncthreads();
    if (out_tiled) {
        // 4 col-tiles of [256][64]; per wave-instruction: 8 rows x 64 cols
        // = 1 KB fully contiguous in the tiled layout.
        const size_t tbase = ((size_t)(m0 >> 8) * (N >> 6) + (n0 >> 6)) * 16384;
        const int rsub = lane >> 3;        // 0..7  (row within 8-row group)
        const int chk  = (lane & 7) * 8;   // 0..56 (u16 chunk within row)
#pragma unroll
        for (int it = 0; it < 16; ++it) {
            int u = it * 8 + wave;         // 0..127 = 4 tiles x 32 row-groups
            int tc = u >> 5;               // col-tile 0..3
            int row = (u & 31) * 8 + rsub; // 0..255
            *(u16x8*)(C + tbase + (size_t)tc * 16384 + row * 64 + chk) =
                *(const u16x8*)(&smem[row * CSTR + tc * 64 + chk]);
        }
    } else {
        const int erow = tid >> 5;         // 0..15
        const int ecol = (tid & 31) * 8;   // 32 lanes x 8 u16 = 256 cols
#pragma unroll
        for (int rr = 0; rr < 16; ++rr) {
            int row = rr * 16 + erow;
            *(u16x8*)(C + (size_t)(m0 + row) * N + n0 + ecol) =
                *(const u16x8*)(&smem[row * CSTR + ecol]);
        }
    }
#undef CSTR
}

// -------- aggregation + final residual (in-place on d_out, f32) --------
// out[t=l*B+b][d] = emb32[t][d] + sum_m (bond[b,l,m]!=l) * msg[bond*B+b][d]
__global__ void agg_kernel(const float* __restrict__ emb32, const u16* __restrict__ msg,
                           const int* __restrict__ bond, float* __restrict__ out) {
    int t = blockIdx.x * 4 + (threadIdx.x >> 6);  // one wave per token
    int lane = threadIdx.x & 63;
    int l = t >> 7, b = t & 127;
    int d = lane * 8;
    float acc[8];
    {
        f32x8 v = *(const f32x8*)(emb32 + (size_t)t * DIM + d);
#pragma unroll
        for (int i = 0; i < 8; i++) acc[i] = v[i];
    }
    const int* bp = bond + ((size_t)b * NL + l) * 6;
#pragma unroll
    for (int m = 0; m < 6; m++) {
        int j = bp[m];
        if (j != l) {  // wave-uniform branch
            u16x8 g = *(const u16x8*)(msg + ((size_t)j * NB + b) * DIM + d);
#pragma unroll
            for (int i = 0; i < 8; i++) acc[i] += bf2f(g[i]);
        }
    }
    f32x8 o;
#pragma unroll
    for (int i = 0; i < 8; i++) o[i] = acc[i];
    *(f32x8*)(out + (size_t)t * DIM + d) = o;
}

extern "C" void kernel_launch(void* const* d_in, const int* in_sizes, int n_in,
                              void* d_out, int out_size, void* d_ws, size_t ws_size,
                              hipStream_t stream) {
    const int* element = (const int*)d_in[0];
    const int* bond    = (const int*)d_in[1];
    const int* aroma   = (const int*)d_in[2];
    const int* charge  = (const int*)d_in[3];
    const int* segment = (const int*)d_in[4];
    const float* pe      = (const float*)d_in[5];
    const float* E_elem  = (const float*)d_in[6];
    const float* E_charge= (const float*)d_in[7];
    const float* E_aroma = (const float*)d_in[8];
    const float* E_seg   = (const float*)d_in[9];
    const float* W1 = (const float*)d_in[10];
    const float* b1 = (const float*)d_in[11];
    const float* W2 = (const float*)d_in[12];
    const float* b2 = (const float*)d_in[13];
    const float* W3 = (const float*)d_in[14];
    const float* b3 = (const float*)d_in[15];
    const float* W4 = (const float*)d_in[16];
    const float* b4 = (const float*)d_in[17];
    const float* W5 = (const float*)d_in[18];
    const float* b5 = (const float*)d_in[19];

    // f32 emb lives in d_out (50 MiB); agg rewrites d_out in place at the end.
    float* emb32 = (float*)d_out;

    // dynamic ws layout — never exceed ws_size
    char* ws = (char*)d_ws;
    size_t woff = 0;
    auto take = [&](size_t bytes) -> u16* {
        u16* p = (u16*)(ws + woff);
        woff += (bytes + 255) & ~(size_t)255;
        return p;
    };
    u16* W1T = take((size_t)HID * DIM * 2);   // 2048x512 bf16
    u16* W2T = take((size_t)DIM * HID * 2);   // 512x2048
    u16* W3T = take((size_t)HID * DIM * 2);
    u16* W4T = take((size_t)DIM * HID * 2);
    u16* W5T = take((size_t)DIM * DIM * 2);
    u16* emb16 = take((size_t)NTOK * DIM * 2);  // 24 MiB (tiled)
    u16* msg   = take((size_t)NTOK * DIM * 2);  // 24 MiB (row-major)

    // pick largest M-chunk that fits: h(CM x HID) + xa,xb(CM x DIM), bf16.
    // CM must be a multiple of 256 (gemm tile height; tiled layout unit).
    static const int ncs[] = {1, 2, 3, 4, 6, 8, 12, 16, 24, 32, 48, 96};
    int CM = 256;
    for (int nc : ncs) {
        int cm = NTOK / nc;
        if (cm % 256 != 0) continue;
        size_t need = woff + ((size_t)cm * HID * 2 + 256)
                           + ((size_t)cm * DIM * 2 + 256) * 2;
        if (need <= ws_size) { CM = cm; break; }
    }
    u16* hC  = take((size_t)CM * HID * 2);   // tiled
    u16* xaC = take((size_t)CM * DIM * 2);   // tiled
    u16* xbC = take((size_t)CM * DIM * 2);   // tiled

    // weight transposes + cast: f32 (K,N) -> bf16 (N,K)
    transpose_f2b<<<dim3(HID / 32, DIM / 32), 256, 0, stream>>>(W1, W1T, DIM, HID);
    transpose_f2b<<<dim3(DIM / 32, HID / 32), 256, 0, stream>>>(W2, W2T, HID, DIM);
    transpose_f2b<<<dim3(HID / 32, DIM / 32), 256, 0, stream>>>(W3, W3T, DIM, HID);
    transpose_f2b<<<dim3(DIM / 32, HID / 32), 256, 0, stream>>>(W4, W4T, HID, DIM);
    transpose_f2b<<<dim3(DIM / 32, DIM / 32), 256, 0, stream>>>(W5, W5T, DIM, DIM);

    embed_kernel<<<NTOK / 4, 256, 0, stream>>>(element, aroma, charge, segment, pe,
                                               E_elem, E_charge, E_aroma, E_seg,
                                               emb32, emb16);

    // MLP per M-chunk: x += relu(x@W1+b1)@W2+b2 ; x += relu(x@W3+b3)@W4+b4 ; msg = x@W5+b5
    // All activations between GEMMs are K-tiled; msg (agg consumer) row-major.
    // Chunk offset within a tiled buffer of row-length K: c0*K (tiles pack
    // M-major: (c0/256)*(K/64)*16384 == c0*K).
    for (int c0 = 0; c0 < NTOK; c0 += CM) {
        const u16* x16 = emb16 + (size_t)c0 * DIM;
        const float* x32 = emb32 + (size_t)c0 * DIM;
        u16* msgC = msg + (size_t)c0 * DIM;
        int mt = CM / 256;
        gemm_bt<<<dim3(mt * (HID / 256)), 512, 0, stream>>>(x16, W1T, b1, nullptr, nullptr, hC,  CM, HID, DIM, 1, 1);
        gemm_bt<<<dim3(mt * (DIM / 256)), 512, 0, stream>>>(hC,  W2T, b2, nullptr, x32,     xaC, CM, DIM, HID, 0, 1);
        gemm_bt<<<dim3(mt * (HID / 256)), 512, 0, stream>>>(xaC, W3T, b3, nullptr, nullptr, hC,  CM, HID, DIM, 1, 1);
        gemm_bt<<<dim3(mt * (DIM / 256)), 512, 0, stream>>>(hC,  W4T, b4, xaC,    nullptr,  xbC, CM, DIM, HID, 0, 1);
        gemm_bt<<<dim3(mt * (DIM / 256)), 512, 0, stream>>>(xbC, W5T, b5, nullptr, nullptr, msgC, CM, DIM, DIM, 0, 0);
    }

    agg_kernel<<<NTOK / 4, 256, 0, stream>>>(emb32, msg, bond, (float*)d_out);
}